// Round 1
// baseline (106.790 us; speedup 1.0000x reference)
//
#include <hip/hip_runtime.h>
#include <math.h>

// Problem dims (fixed by reference setup_inputs)
#define B 2
#define C 128
#define H 128
#define W 256
#define K 20

// One block per (b,h). 256 threads = 4 waves; thread tid owns w = tid in phase C.
__global__ __launch_bounds__(256) void isomax_kernel(
    const float* __restrict__ feats,    // [B,C,H,W]
    const float* __restrict__ protos,   // [K,C]
    const float* __restrict__ dscale,   // [1]
    float* __restrict__ out)            // [B,K,H,W]
{
    __shared__ __align__(16) float s_pn[C * K];  // normalized prototypes, TRANSPOSED [c][K] (10 KB)
    __shared__ float s_rn[C];                    // 1/max(||features[b,c,h,:]||, eps)
    __shared__ float s_rp[K];                    // 1/max(||proto[k,:]||, eps)

    const int tid = threadIdx.x;
    const int bh  = blockIdx.x;
    const int b   = bh / H;
    const int h   = bh % H;

    // ---- Phase A1: prototype row norms (tiny: 20 rows x 128) ----
    if (tid < K) {
        float ss = 0.f;
        const float* p = protos + tid * C;
        for (int c = 0; c < C; ++c) { float v = p[c]; ss = fmaf(v, v, ss); }
        s_rp[tid] = 1.0f / fmaxf(sqrtf(ss), 1e-12f);
    }
    __syncthreads();

    // ---- Phase A2: normalized prototypes into LDS, transposed to [c][K] ----
    for (int i = tid; i < K * C; i += 256) {
        int k = i >> 7;        // i / C
        int c = i & (C - 1);   // i % C
        s_pn[c * K + k] = protos[i] * s_rp[k];
    }

    // ---- Phase B: per-(b,c,h) norms over W (the dim=1 quirk) ----
    // wave 0..3 handle c = wave, wave+4, ...; each wave reduces one 256-float row
    const int wave = tid >> 6;
    const int lane = tid & 63;
    for (int c = wave; c < C; c += 4) {
        const float* row = feats + ((size_t)((b * C + c) * H + h)) * W;
        float4 v = ((const float4*)row)[lane];   // 64 lanes x float4 = 256 floats
        float ss = fmaf(v.x, v.x, fmaf(v.y, v.y, fmaf(v.z, v.z, v.w * v.w)));
        #pragma unroll
        for (int off = 32; off > 0; off >>= 1)
            ss += __shfl_xor(ss, off, 64);
        if (lane == 0) s_rn[c] = 1.0f / fmaxf(sqrtf(ss), 1e-12f);
    }
    __syncthreads();   // covers both s_pn and s_rn

    // ---- Phase C: distances. thread owns w = tid. ----
    float acc[K];
    #pragma unroll
    for (int k = 0; k < K; ++k) acc[k] = 0.f;

    const float* fcol = feats + ((size_t)(b * C) * H + h) * W + tid;
    #pragma unroll 4
    for (int c = 0; c < C; ++c) {
        float v = fcol[(size_t)c * H * W] * s_rn[c];   // coalesced over w
        const float4* pn4 = (const float4*)(&s_pn[c * K]);  // c*80 bytes, 16B-aligned
        #pragma unroll
        for (int q = 0; q < 5; ++q) {
            float4 p = pn4[q];   // broadcast ds_read_b128
            float d0 = v - p.x; acc[q * 4 + 0] = fmaf(d0, d0, acc[q * 4 + 0]);
            float d1 = v - p.y; acc[q * 4 + 1] = fmaf(d1, d1, acc[q * 4 + 1]);
            float d2 = v - p.z; acc[q * 4 + 2] = fmaf(d2, d2, acc[q * 4 + 2]);
            float d3 = v - p.w; acc[q * 4 + 3] = fmaf(d3, d3, acc[q * 4 + 3]);
        }
    }

    // ---- Epilogue: logits[b,k,h,w] = -|scale| * sqrt(acc[k]) ----
    const float scale = fabsf(dscale[0]);
    float* ob = out + ((size_t)(b * K) * H + h) * W + tid;
    #pragma unroll
    for (int k = 0; k < K; ++k) {
        ob[(size_t)k * H * W] = -scale * sqrtf(acc[k]);
    }
}

extern "C" void kernel_launch(void* const* d_in, const int* in_sizes, int n_in,
                              void* d_out, int out_size, void* d_ws, size_t ws_size,
                              hipStream_t stream) {
    const float* feats  = (const float*)d_in[0];
    const float* protos = (const float*)d_in[1];
    const float* dscale = (const float*)d_in[2];
    float* out = (float*)d_out;

    isomax_kernel<<<B * H, 256, 0, stream>>>(feats, protos, dscale, out);
}

// Round 2
// 92.830 us; speedup vs baseline: 1.1504x; 1.1504x over previous
//
#include <hip/hip_runtime.h>
#include <math.h>

// Problem dims (fixed by reference setup_inputs)
#define B 2
#define C 128
#define H 128
#define W 256
#define K 20
#define NT 512        // threads per block (8 waves)
#define WTILE 128     // w positions per block (W split in halves)
#define NCCH 4        // c-chunks
#define CCH 32        // c per chunk

// Grid = B*H*2 (w-halves), block = 512. Thread = (c-chunk, w-local).
// 2 blocks/CU * 8 waves = 16 waves/CU -> latency hiding the round-1 kernel lacked.
__global__ __launch_bounds__(NT, 4) void isomax_kernel(
    const float* __restrict__ feats,    // [B,C,H,W]
    const float* __restrict__ protos,   // [K,C]
    const float* __restrict__ dscale,   // [1]
    float* __restrict__ out)            // [B,K,H,W]
{
    __shared__ __align__(16) float s_pn[C * K];      // normalized prototypes, [c][K], 10 KB
    __shared__ float s_rn[C];                        // 1/max(||feats[b,c,h,:]||, eps)
    __shared__ float s_rp[K];
    __shared__ float s_red[NCCH][K][WTILE];          // partial dist^2, 40 KB, conflict-free layout

    const int tid   = threadIdx.x;
    const int blk   = blockIdx.x;
    const int whalf = blk & 1;
    const int bh    = blk >> 1;
    const int b     = bh / H;
    const int h     = bh % H;
    const int wave  = tid >> 6;
    const int lane  = tid & 63;

    // ---- A1: prototype inverse norms (wave-parallel over k) ----
    for (int k = wave; k < K; k += 8) {
        const float* p = protos + k * C;
        float v0 = p[lane], v1 = p[lane + 64];
        float ss = fmaf(v0, v0, v1 * v1);
        #pragma unroll
        for (int off = 32; off > 0; off >>= 1)
            ss += __shfl_xor(ss, off, 64);
        if (lane == 0) s_rp[k] = 1.0f / fmaxf(sqrtf(ss), 1e-12f);
    }

    // ---- B: per-(b,c,h) inverse norms over W (the dim=1 quirk) ----
    // 8 waves, 16 rows each; 64 lanes x float4 = one 256-float row per wave
    for (int c = wave; c < C; c += 8) {
        const float* row = feats + ((size_t)((b * C + c) * H + h)) * W;
        float4 v = ((const float4*)row)[lane];
        float ss = fmaf(v.x, v.x, fmaf(v.y, v.y, fmaf(v.z, v.z, v.w * v.w)));
        #pragma unroll
        for (int off = 32; off > 0; off >>= 1)
            ss += __shfl_xor(ss, off, 64);
        if (lane == 0) s_rn[c] = 1.0f / fmaxf(sqrtf(ss), 1e-12f);
    }
    __syncthreads();   // s_rp + s_rn ready

    // ---- A2: normalized prototypes transposed into LDS [c][K] ----
    for (int i = tid; i < K * C; i += NT) {
        int k = i >> 7;        // i / C
        int c = i & (C - 1);   // i % C
        s_pn[c * K + k] = protos[i] * s_rp[k];
    }
    __syncthreads();   // s_pn ready

    // ---- C: partial distances. thread = (c-chunk, w-local). ----
    const int wl  = tid & (WTILE - 1);
    const int cch = tid >> 7;          // 0..3, wave-uniform (128 | 64)
    const int w   = whalf * WTILE + wl;

    float acc[K];
    #pragma unroll
    for (int k = 0; k < K; ++k) acc[k] = 0.f;

    const float* fcol = feats + ((size_t)(b * C) * H + h) * W + w;
    const int c0 = cch * CCH;
    #pragma unroll 4
    for (int ci = 0; ci < CCH; ++ci) {
        const int c = c0 + ci;
        float v = fcol[(size_t)c * (H * W)] * s_rn[c];   // coalesced over w
        const float4* pn4 = (const float4*)(&s_pn[c * K]);
        #pragma unroll
        for (int q = 0; q < 5; ++q) {
            float4 p = pn4[q];   // broadcast ds_read_b128
            float d0 = v - p.x; acc[q * 4 + 0] = fmaf(d0, d0, acc[q * 4 + 0]);
            float d1 = v - p.y; acc[q * 4 + 1] = fmaf(d1, d1, acc[q * 4 + 1]);
            float d2 = v - p.z; acc[q * 4 + 2] = fmaf(d2, d2, acc[q * 4 + 2]);
            float d3 = v - p.w; acc[q * 4 + 3] = fmaf(d3, d3, acc[q * 4 + 3]);
        }
    }

    // write partials: [cch][k][wl] — lanes consecutive in wl => conflict-free
    #pragma unroll
    for (int k = 0; k < K; ++k) s_red[cch][k][wl] = acc[k];
    __syncthreads();

    // ---- Reduce + epilogue: 20*128 = 2560 outputs, 512 threads -> 5 each ----
    const float scale = fabsf(dscale[0]);
    const int ow = tid & (WTILE - 1);
    const int kg = tid >> 7;           // 0..3 -> k in [kg*5, kg*5+5)
    float* ob = out + ((size_t)(b * K) * H + h) * W + whalf * WTILE + ow;
    #pragma unroll
    for (int j = 0; j < 5; ++j) {
        const int k = kg * 5 + j;
        float s = s_red[0][k][ow] + s_red[1][k][ow] + s_red[2][k][ow] + s_red[3][k][ow];
        ob[(size_t)k * (H * W)] = -scale * sqrtf(s);   // coalesced over w per k
    }
}

extern "C" void kernel_launch(void* const* d_in, const int* in_sizes, int n_in,
                              void* d_out, int out_size, void* d_ws, size_t ws_size,
                              hipStream_t stream) {
    const float* feats  = (const float*)d_in[0];
    const float* protos = (const float*)d_in[1];
    const float* dscale = (const float*)d_in[2];
    float* out = (float*)d_out;

    isomax_kernel<<<B * H * 2, NT, 0, stream>>>(feats, protos, dscale, out);
}